// Round 5
// baseline (188.491 us; speedup 1.0000x reference)
//
#include <hip/hip_runtime.h>
#include <hip/hip_bf16.h>

// Problem constants (B=4, S=2048 -> 8192 tokens; D=O=1024; E=8; top-2)
#define NTOK 8192
#define DDIM 1024
#define ODIM 1024
#define NEXP 8
#define BK   32
#define NKT  (DDIM / BK)     // 32 K-tiles

typedef __attribute__((ext_vector_type(8))) short short8;
typedef __attribute__((ext_vector_type(4))) float f32x4;

// ---- workspace layout (bytes) ----
#define CNT_OFF   0u                               // 16 ints (expert x rank)
#define SC_OFF    (4u * 1024u)                     // 8192*2 floats
#define LIST_OFF  (128u * 1024u)                   // 16*8192 ints = 512 KiB
#define XH_OFF    (1u << 20)                       // bf16 x, 16 MiB
#define WH_OFF    ((1u << 20) + 16u*1024u*1024u)   // bf16 W, 16 MiB
#define O2_OFF    ((1u << 20) + 32u*1024u*1024u)   // rank-1 accum, 32 MiB
#define WS_NEED   ((size_t)O2_OFF + (size_t)NTOK * ODIM * 4u)

__device__ inline unsigned short f2bf(float f) {
    unsigned int u = __float_as_uint(f);
    unsigned int r = (u + 0x7FFFu + ((u >> 16) & 1u)) >> 16;   // RNE
    return (unsigned short)r;
}

__device__ inline void glds16(const unsigned short* g, unsigned short* l) {
    __builtin_amdgcn_global_load_lds(
        (const __attribute__((address_space(1))) unsigned int*)g,
        (__attribute__((address_space(3))) unsigned int*)l, 16, 0, 0);
}

// W fp32->bf16; block 0 also zeroes the 16 expertxrank counts (runs pre-gate)
__global__ void k_cvtw(const float4* __restrict__ src, ushort4* __restrict__ dst,
                       int n4, int* __restrict__ counts) {
    if (blockIdx.x == 0 && threadIdx.x < 16) counts[threadIdx.x] = 0;
    int i = blockIdx.x * blockDim.x + threadIdx.x;
    if (i >= n4) return;
    float4 v = src[i];
    ushort4 o;
    o.x = f2bf(v.x); o.y = f2bf(v.y); o.z = f2bf(v.z); o.w = f2bf(v.w);
    dst[i] = o;
}

// Gating: 1024 blocks x 8 tokens (2 per wave) -> 4 blocks/CU for latency hiding.
// fp64 dot+butterfly decides top-k order (bit-stable vs prior passing rounds);
// softmax weights via fp32 expf (order-independent). Block-aggregated scatter
// into 16 (expert x rank) lists; fused bf16-cvt of x and out = s0*b0 + s1*b1.
__global__ __launch_bounds__(256, 2) void k_gate(
    const float* __restrict__ x, const float* __restrict__ Wg,
    const float* __restrict__ bg, const float* __restrict__ b,
    float* __restrict__ out, float* __restrict__ scores2,
    int* __restrict__ lists, int* __restrict__ counts,
    unsigned short* __restrict__ xh)
{
    __shared__ unsigned char s_eid[16];     // 8 tokens * 2 entries
    const int tid = threadIdx.x, wave = tid >> 6, lane = tid & 63;
    const int tblk = blockIdx.x * 8;

    #pragma unroll 1
    for (int ti = 0; ti < 2; ti++) {
        const int t = tblk + wave * 2 + ti;
        const float* xr = x + (size_t)t * DDIM;
        float4 xv[4];
        #pragma unroll
        for (int i = 0; i < 4; i++)
            xv[i] = *(const float4*)&xr[lane * 4 + 256 * i];

        unsigned short* xhr = xh + (size_t)t * DDIM;
        #pragma unroll
        for (int i = 0; i < 4; i++) {
            ushort4 h;
            h.x = f2bf(xv[i].x); h.y = f2bf(xv[i].y);
            h.z = f2bf(xv[i].z); h.w = f2bf(xv[i].w);
            *(ushort4*)&xhr[lane * 4 + 256 * i] = h;
        }

        double lg[NEXP];
        #pragma unroll
        for (int e = 0; e < NEXP; e++) {
            const float* wr = Wg + (size_t)e * DDIM;
            double a = 0.0;
            #pragma unroll
            for (int i = 0; i < 4; i++) {
                float4 wv = *(const float4*)&wr[lane * 4 + 256 * i];
                a += (double)xv[i].x * (double)wv.x + (double)xv[i].y * (double)wv.y
                   + (double)xv[i].z * (double)wv.z + (double)xv[i].w * (double)wv.w;
            }
            #pragma unroll
            for (int off = 32; off > 0; off >>= 1) a += __shfl_xor(a, off);
            lg[e] = a + (double)bg[e];
        }

        int i0 = -1, i1 = -1;
        double best = -1e300, sec = -1e300;
        #pragma unroll
        for (int e = 0; e < NEXP; e++) {
            double v = lg[e];
            if (v > best) { sec = best; i1 = i0; best = v; i0 = e; }
            else if (v > sec) { sec = v; i1 = e; }
        }
        float sum = 0.f;
        #pragma unroll
        for (int e = 0; e < NEXP; e++) sum += expf((float)(lg[e] - best));
        float s0 = 1.f / sum;
        float s1 = expf((float)(sec - best)) / sum;

        if (lane == 0) {
            scores2[t * 2 + 0] = s0;
            scores2[t * 2 + 1] = s1;
            int le = (wave * 2 + ti) * 2;
            s_eid[le + 0] = (unsigned char)i0;
            s_eid[le + 1] = (unsigned char)i1;
        }

        const float* b0 = b + (size_t)i0 * ODIM;
        const float* b1 = b + (size_t)i1 * ODIM;
        float* orow = out + (size_t)t * ODIM;
        #pragma unroll
        for (int i = 0; i < 4; i++) {
            int o = lane * 4 + 256 * i;
            float4 v0 = *(const float4*)&b0[o];
            float4 v1 = *(const float4*)&b1[o];
            float4 r;
            r.x = s0 * v0.x + s1 * v1.x;
            r.y = s0 * v0.y + s1 * v1.y;
            r.z = s0 * v0.z + s1 * v1.z;
            r.w = s0 * v0.w + s1 * v1.w;
            *(float4*)&orow[o] = r;
        }
    }
    __syncthreads();

    // 16 owners: e = tid&7, rank = tid>>3; one global atomic per (block,owner)
    if (tid < 16) {
        int e = tid & 7, kk = tid >> 3;
        int c = 0;
        #pragma unroll
        for (int j = 0; j < 8; j++) c += (s_eid[j * 2 + kk] == e);
        if (c) {
            int p = atomicAdd(&counts[tid], c);
            #pragma unroll
            for (int j = 0; j < 8; j++)
                if (s_eid[j * 2 + kk] == e)
                    lists[tid * NTOK + (p++)] = (tblk + j) * 2 + kk;
        }
    }
}

// Grouped GEMM over 16 (expert x rank) lists in ONE dispatch. 128x128 tile,
// BK=32 double-buffered (32 KiB LDS -> 4 blocks/CU), XOR seg-swizzle
// (phys = seg ^ ((row>>1)&3); 2-way bank access = free). Persistent-stride
// tile loop with per-block prefix decode. Rank-0 tiles RMW `out` (bias-init
// by gate); rank-1 tiles pure-STORE into out2 (race-free, no read).
__global__ __launch_bounds__(256, 4) void k_gemm(
    const unsigned short* __restrict__ xh, const unsigned short* __restrict__ wh,
    const int* __restrict__ counts, const int* __restrict__ lists,
    const float* __restrict__ scores2, float* __restrict__ out,
    float* __restrict__ out2, int listLo, int listHi)
{
    __shared__ __align__(16) unsigned short As[2][128 * BK];
    __shared__ __align__(16) unsigned short Bs[2][128 * BK];

    const int nwg = (int)gridDim.x;
    const int bid0 = ((int)blockIdx.x & 7) * (nwg >> 3) + ((int)blockIdx.x >> 3);
    const int tid = threadIdx.x, wid = tid >> 6, lane = tid & 63;

    int cnts[16];
    #pragma unroll
    for (int i = 0; i < 16; i++) cnts[i] = counts[i];
    int tbLo = 0, tbHi = 0;
    #pragma unroll
    for (int i = 0; i < 16; i++) {
        int nt_ = ((cnts[i] + 127) >> 7) * 8;
        if (i < listLo) tbLo += nt_;
        if (i < listHi) tbHi += nt_;
    }

    const int rl = lane >> 2;               // row-in-call
    const int wm = wid >> 1, wn = wid & 1;
    const int fr = lane & 15, g4 = lane >> 4;

    #pragma unroll 1
    for (int tile = tbLo + bid0; tile < tbHi; tile += nwg) {
        // decode tile -> (list li, m-tile, n-tile)
        int li = 0, base = 0, cnt = 0, acc_ = 0;
        #pragma unroll
        for (int i = 0; i < 16; i++) {
            int nt_ = ((cnts[i] + 127) >> 7) * 8;
            if (tile >= acc_) { li = i; base = acc_; cnt = cnts[i]; }
            acc_ += nt_;
        }
        const int local = tile - base, mt = local >> 3, ntc = local & 7;
        const int m0 = mt * 128, n0 = ntc * 128;
        const int* list = lists + li * NTOK;
        const unsigned short* whE = wh + (size_t)(li & 7) * ODIM * DDIM;
        const bool st = (out2 != nullptr) && (li >= 8);

        // staging: 2 calls per matrix; call i covers rows wid*32+i*16..+15
        const unsigned short* aS[2];
        const unsigned short* bS[2];
        int rb[2];
        #pragma unroll
        for (int i = 0; i < 2; i++) {
            int R = wid * 32 + i * 16 + rl;
            int sl = (lane & 3) ^ ((R >> 1) & 3);       // inverse-swizzled seg
            int g = m0 + R; if (g >= cnt) g = cnt - 1;
            aS[i] = xh + (size_t)(list[g] >> 1) * DDIM + sl * 8;
            bS[i] = whE + (size_t)(n0 + R) * DDIM + sl * 8;
            rb[i] = (wid * 32 + i * 16) * BK;
        }

        f32x4 acc[4][4];
        #pragma unroll
        for (int m = 0; m < 4; m++)
            #pragma unroll
            for (int n = 0; n < 4; n++)
                acc[m][n] = (f32x4){0.f, 0.f, 0.f, 0.f};

        #pragma unroll
        for (int i = 0; i < 2; i++) {
            glds16(aS[i], &As[0][rb[i]]);
            glds16(bS[i], &Bs[0][rb[i]]);
        }

        int buf = 0;
        #pragma unroll 1
        for (int t = 0; t < NKT; t++) {
            __syncthreads();                 // stage(t) landed (vmcnt drain)
            if (t + 1 < NKT) {
                const int k0 = (t + 1) * BK;
                #pragma unroll
                for (int i = 0; i < 2; i++) {
                    glds16(aS[i] + k0, &As[buf ^ 1][rb[i]]);
                    glds16(bS[i] + k0, &Bs[buf ^ 1][rb[i]]);
                }
            }
            short8 af[4], bf_[4];
            #pragma unroll
            for (int m = 0; m < 4; m++) {
                int R = wm * 64 + m * 16 + fr;
                int ph = g4 ^ ((R >> 1) & 3);
                af[m] = *(const short8*)&As[buf][R * BK + ph * 8];
            }
            #pragma unroll
            for (int n = 0; n < 4; n++) {
                int R = wn * 64 + n * 16 + fr;
                int ph = g4 ^ ((R >> 1) & 3);
                bf_[n] = *(const short8*)&Bs[buf][R * BK + ph * 8];
            }
            #pragma unroll
            for (int m = 0; m < 4; m++)
                #pragma unroll
                for (int n = 0; n < 4; n++)
                    acc[m][n] = __builtin_amdgcn_mfma_f32_16x16x32_bf16(
                        af[m], bf_[n], acc[m][n], 0, 0, 0);
            buf ^= 1;
        }

        // epilogue (C/D: col=lane&15, row=(lane>>4)*4+j)
        #pragma unroll
        for (int m = 0; m < 4; m++) {
            #pragma unroll
            for (int j = 0; j < 4; j++) {
                int r = wm * 64 + m * 16 + g4 * 4 + j;
                int gr = m0 + r;
                if (gr < cnt) {
                    int entry = list[gr];
                    float s = scores2[entry];
                    float* orow = (st ? out2 : out)
                                  + (size_t)(entry >> 1) * ODIM + n0 + wn * 64 + fr;
                    if (st) {
                        #pragma unroll
                        for (int n = 0; n < 4; n++) orow[n * 16] = s * acc[m][n][j];
                    } else {
                        #pragma unroll
                        for (int n = 0; n < 4; n++) orow[n * 16] += s * acc[m][n][j];
                    }
                }
            }
        }
    }
}

__global__ void k_add(float4* __restrict__ out, const float4* __restrict__ out2, int n4) {
    int i = blockIdx.x * blockDim.x + threadIdx.x;
    const int stride = gridDim.x * blockDim.x;
    #pragma unroll 1
    for (; i < n4; i += stride) {
        float4 a = out[i], c = out2[i];
        a.x += c.x; a.y += c.y; a.z += c.z; a.w += c.w;
        out[i] = a;
    }
}

extern "C" void kernel_launch(void* const* d_in, const int* in_sizes, int n_in,
                              void* d_out, int out_size, void* d_ws, size_t ws_size,
                              hipStream_t stream) {
    const float* x  = (const float*)d_in[0];
    const float* W  = (const float*)d_in[1];
    const float* b  = (const float*)d_in[2];
    const float* Wg = (const float*)d_in[3];
    const float* bg = (const float*)d_in[4];
    float* out = (float*)d_out;
    char* ws = (char*)d_ws;

    int*   counts  = (int*)(ws + CNT_OFF);    // [16]: rank0 experts, rank1 experts
    float* scores2 = (float*)(ws + SC_OFF);
    int*   lists   = (int*)(ws + LIST_OFF);   // [16][NTOK]
    unsigned short* xh = (unsigned short*)(ws + XH_OFF);
    unsigned short* wh = (unsigned short*)(ws + WH_OFF);
    float* out2 = (float*)(ws + O2_OFF);

    int n4w = NEXP * ODIM * DDIM / 4;
    k_cvtw<<<n4w / 256, 256, 0, stream>>>((const float4*)W, (ushort4*)wh, n4w, counts);

    k_gate<<<NTOK / 8, 256, 0, stream>>>(x, Wg, bg, b, out, scores2, lists, counts, xh);

    if (ws_size >= WS_NEED) {
        // merged: one dispatch over all 16 lists; rank-1 stores to out2
        k_gemm<<<1024, 256, 0, stream>>>(xh, wh, counts, lists, scores2, out, out2, 0, 16);
        k_add<<<2048, 256, 0, stream>>>((float4*)out, (const float4*)out2, NTOK * ODIM / 4);
    } else {
        // fallback: two stream-ordered RMW passes (round-4 behavior)
        k_gemm<<<1024, 256, 0, stream>>>(xh, wh, counts, lists, scores2, out, nullptr, 0, 8);
        k_gemm<<<1024, 256, 0, stream>>>(xh, wh, counts, lists, scores2, out, nullptr, 8, 16);
    }
}

// Round 6
// 140.442 us; speedup vs baseline: 1.3421x; 1.3421x over previous
//
#include <hip/hip_runtime.h>
#include <hip/hip_bf16.h>

// Problem constants (B=4, S=2048 -> 8192 tokens; D=O=1024; E=8; top-2)
#define NTOK 8192
#define DDIM 1024
#define ODIM 1024
#define NEXP 8
#define BK   32
#define NKT  (DDIM / BK)     // 32 K-tiles

typedef __attribute__((ext_vector_type(8))) short short8;
typedef __attribute__((ext_vector_type(4))) float f32x4;

// ---- workspace layout (bytes) ----
#define CNT_OFF   0u                               // 16 ints (expert x rank)
#define SC_OFF    (4u * 1024u)                     // 8192*2 floats
#define LIST_OFF  (128u * 1024u)                   // 16*8192 ints = 512 KiB
#define XH_OFF    (1u << 20)                       // bf16 x, 16 MiB
#define WH_OFF    ((1u << 20) + 16u*1024u*1024u)   // bf16 W, 16 MiB
#define O2_OFF    ((1u << 20) + 32u*1024u*1024u)   // rank-1 accum, 32 MiB
#define WS_NEED   ((size_t)O2_OFF + (size_t)NTOK * ODIM * 4u)

__device__ inline unsigned short f2bf(float f) {
    unsigned int u = __float_as_uint(f);
    unsigned int r = (u + 0x7FFFu + ((u >> 16) & 1u)) >> 16;   // RNE
    return (unsigned short)r;
}

__device__ inline void glds16(const unsigned short* g, unsigned short* l) {
    __builtin_amdgcn_global_load_lds(
        (const __attribute__((address_space(1))) unsigned int*)g,
        (__attribute__((address_space(3))) unsigned int*)l, 16, 0, 0);
}

// W fp32->bf16; block 0 also zeroes the 16 expertxrank counts (runs pre-gate)
__global__ void k_cvtw(const float4* __restrict__ src, ushort4* __restrict__ dst,
                       int n4, int* __restrict__ counts) {
    if (blockIdx.x == 0 && threadIdx.x < 16) counts[threadIdx.x] = 0;
    int i = blockIdx.x * blockDim.x + threadIdx.x;
    if (i >= n4) return;
    float4 v = src[i];
    ushort4 o;
    o.x = f2bf(v.x); o.y = f2bf(v.y); o.z = f2bf(v.z); o.w = f2bf(v.w);
    dst[i] = o;
}

// Gating: 1024 blocks x 8 tokens (2 per wave). NO min-waves clamp: round 5's
// (256,2) capped VGPR at 128 and spilled ~44 regs/thread -> ~180 MB scratch
// traffic (FETCH 102/WRITE 135 MB observed) -> 107us. Bias-init of out moved
// to the GEMM epilogue, so gate only: fp64 top-k, scores, lists, bf16 x.
__global__ __launch_bounds__(256) void k_gate(
    const float* __restrict__ x, const float* __restrict__ Wg,
    const float* __restrict__ bg, float* __restrict__ scores2,
    int* __restrict__ lists, int* __restrict__ counts,
    unsigned short* __restrict__ xh)
{
    __shared__ unsigned char s_eid[16];     // 8 tokens * 2 entries
    const int tid = threadIdx.x, wave = tid >> 6, lane = tid & 63;
    const int tblk = blockIdx.x * 8;

    #pragma unroll 1
    for (int ti = 0; ti < 2; ti++) {
        const int t = tblk + wave * 2 + ti;
        const float* xr = x + (size_t)t * DDIM;
        float4 xv[4];
        #pragma unroll
        for (int i = 0; i < 4; i++)
            xv[i] = *(const float4*)&xr[lane * 4 + 256 * i];

        unsigned short* xhr = xh + (size_t)t * DDIM;
        #pragma unroll
        for (int i = 0; i < 4; i++) {
            ushort4 h;
            h.x = f2bf(xv[i].x); h.y = f2bf(xv[i].y);
            h.z = f2bf(xv[i].z); h.w = f2bf(xv[i].w);
            *(ushort4*)&xhr[lane * 4 + 256 * i] = h;
        }

        double lg[NEXP];
        #pragma unroll
        for (int e = 0; e < NEXP; e++) {
            const float* wr = Wg + (size_t)e * DDIM;
            double a = 0.0;
            #pragma unroll
            for (int i = 0; i < 4; i++) {
                float4 wv = *(const float4*)&wr[lane * 4 + 256 * i];
                a += (double)xv[i].x * (double)wv.x + (double)xv[i].y * (double)wv.y
                   + (double)xv[i].z * (double)wv.z + (double)xv[i].w * (double)wv.w;
            }
            #pragma unroll
            for (int off = 32; off > 0; off >>= 1) a += __shfl_xor(a, off);
            lg[e] = a + (double)bg[e];
        }

        int i0 = -1, i1 = -1;
        double best = -1e300, sec = -1e300;
        #pragma unroll
        for (int e = 0; e < NEXP; e++) {
            double v = lg[e];
            if (v > best) { sec = best; i1 = i0; best = v; i0 = e; }
            else if (v > sec) { sec = v; i1 = e; }
        }
        float sum = 0.f;
        #pragma unroll
        for (int e = 0; e < NEXP; e++) sum += expf((float)(lg[e] - best));
        float s0 = 1.f / sum;
        float s1 = expf((float)(sec - best)) / sum;

        if (lane == 0) {
            scores2[t * 2 + 0] = s0;
            scores2[t * 2 + 1] = s1;
            int le = (wave * 2 + ti) * 2;
            s_eid[le + 0] = (unsigned char)i0;
            s_eid[le + 1] = (unsigned char)i1;
        }
    }
    __syncthreads();

    // 16 owners: e = tid&7, rank = tid>>3; one global atomic per (block,owner)
    if (tid < 16) {
        int e = tid & 7, kk = tid >> 3;
        int c = 0;
        #pragma unroll
        for (int j = 0; j < 8; j++) c += (s_eid[j * 2 + kk] == e);
        if (c) {
            int p = atomicAdd(&counts[tid], c);
            #pragma unroll
            for (int j = 0; j < 8; j++)
                if (s_eid[j * 2 + kk] == e)
                    lists[tid * NTOK + (p++)] = (tblk + j) * 2 + kk;
        }
    }
}

// Grouped GEMM over 16 (expert x rank) lists in ONE dispatch. 128x128 tile,
// BK=32 double-buffered (32 KiB LDS -> 4 blocks/CU), XOR seg-swizzle.
// Bias folded into the epilogue: out_row = s * (acc + b[e]) -> both ranks are
// PURE STORES (rank-0 -> out, rank-1 -> out2; no RMW fetch). Fallback
// (out2==nullptr): rank-0 stores, rank-1 RMWs in a second stream-ordered pass.
__global__ __launch_bounds__(256, 4) void k_gemm(
    const unsigned short* __restrict__ xh, const unsigned short* __restrict__ wh,
    const int* __restrict__ counts, const int* __restrict__ lists,
    const float* __restrict__ scores2, const float* __restrict__ bias,
    float* __restrict__ out, float* __restrict__ out2, int listLo, int listHi)
{
    __shared__ __align__(16) unsigned short As[2][128 * BK];
    __shared__ __align__(16) unsigned short Bs[2][128 * BK];

    const int nwg = (int)gridDim.x;
    const int bid0 = ((int)blockIdx.x & 7) * (nwg >> 3) + ((int)blockIdx.x >> 3);
    const int tid = threadIdx.x, wid = tid >> 6, lane = tid & 63;

    int cnts[16];
    #pragma unroll
    for (int i = 0; i < 16; i++) cnts[i] = counts[i];
    int tbLo = 0, tbHi = 0;
    #pragma unroll
    for (int i = 0; i < 16; i++) {
        int nt_ = ((cnts[i] + 127) >> 7) * 8;
        if (i < listLo) tbLo += nt_;
        if (i < listHi) tbHi += nt_;
    }

    const int rl = lane >> 2;               // row-in-call
    const int wm = wid >> 1, wn = wid & 1;
    const int fr = lane & 15, g4 = lane >> 4;

    #pragma unroll 1
    for (int tile = tbLo + bid0; tile < tbHi; tile += nwg) {
        // decode tile -> (list li, m-tile, n-tile)
        int li = 0, base = 0, cnt = 0, acc_ = 0;
        #pragma unroll
        for (int i = 0; i < 16; i++) {
            int nt_ = ((cnts[i] + 127) >> 7) * 8;
            if (tile >= acc_) { li = i; base = acc_; cnt = cnts[i]; }
            acc_ += nt_;
        }
        const int local = tile - base, mt = local >> 3, ntc = local & 7;
        const int m0 = mt * 128, n0 = ntc * 128;
        const int* list = lists + li * NTOK;
        const int exp_ = li & 7;
        const unsigned short* whE = wh + (size_t)exp_ * ODIM * DDIM;

        const unsigned short* aS[2];
        const unsigned short* bS[2];
        int rb[2];
        #pragma unroll
        for (int i = 0; i < 2; i++) {
            int R = wid * 32 + i * 16 + rl;
            int sl = (lane & 3) ^ ((R >> 1) & 3);       // inverse-swizzled seg
            int g = m0 + R; if (g >= cnt) g = cnt - 1;
            aS[i] = xh + (size_t)(list[g] >> 1) * DDIM + sl * 8;
            bS[i] = whE + (size_t)(n0 + R) * DDIM + sl * 8;
            rb[i] = (wid * 32 + i * 16) * BK;
        }

        f32x4 acc[4][4];
        #pragma unroll
        for (int m = 0; m < 4; m++)
            #pragma unroll
            for (int n = 0; n < 4; n++)
                acc[m][n] = (f32x4){0.f, 0.f, 0.f, 0.f};

        #pragma unroll
        for (int i = 0; i < 2; i++) {
            glds16(aS[i], &As[0][rb[i]]);
            glds16(bS[i], &Bs[0][rb[i]]);
        }

        int buf = 0;
        #pragma unroll 1
        for (int t = 0; t < NKT; t++) {
            __syncthreads();                 // stage(t) landed (vmcnt drain)
            if (t + 1 < NKT) {
                const int k0 = (t + 1) * BK;
                #pragma unroll
                for (int i = 0; i < 2; i++) {
                    glds16(aS[i] + k0, &As[buf ^ 1][rb[i]]);
                    glds16(bS[i] + k0, &Bs[buf ^ 1][rb[i]]);
                }
            }
            short8 af[4], bf_[4];
            #pragma unroll
            for (int m = 0; m < 4; m++) {
                int R = wm * 64 + m * 16 + fr;
                int ph = g4 ^ ((R >> 1) & 3);
                af[m] = *(const short8*)&As[buf][R * BK + ph * 8];
            }
            #pragma unroll
            for (int n = 0; n < 4; n++) {
                int R = wn * 64 + n * 16 + fr;
                int ph = g4 ^ ((R >> 1) & 3);
                bf_[n] = *(const short8*)&Bs[buf][R * BK + ph * 8];
            }
            #pragma unroll
            for (int m = 0; m < 4; m++)
                #pragma unroll
                for (int n = 0; n < 4; n++)
                    acc[m][n] = __builtin_amdgcn_mfma_f32_16x16x32_bf16(
                        af[m], bf_[n], acc[m][n], 0, 0, 0);
            buf ^= 1;
        }

        // epilogue (C/D: col=lane&15, row=(lane>>4)*4+j); bias folded:
        // out_row = s * (acc + b[e])  (pure store; rank-1 RMW only in fallback)
        const bool rank1 = (li >= 8);
        float* dstBase = (rank1 && out2 != nullptr) ? out2 : out;
        const bool rmw = rank1 && (out2 == nullptr);
        const float* brow = bias + (size_t)exp_ * ODIM + n0 + wn * 64 + fr;
        float bv[4];
        #pragma unroll
        for (int n = 0; n < 4; n++) bv[n] = brow[n * 16];

        #pragma unroll
        for (int m = 0; m < 4; m++) {
            #pragma unroll
            for (int j = 0; j < 4; j++) {
                int r = wm * 64 + m * 16 + g4 * 4 + j;
                int gr = m0 + r;
                if (gr < cnt) {
                    int entry = list[gr];
                    float s = scores2[entry];
                    float* orow = dstBase + (size_t)(entry >> 1) * ODIM + n0 + wn * 64 + fr;
                    if (rmw) {
                        #pragma unroll
                        for (int n = 0; n < 4; n++)
                            orow[n * 16] += s * (acc[m][n][j] + bv[n]);
                    } else {
                        #pragma unroll
                        for (int n = 0; n < 4; n++)
                            orow[n * 16] = s * (acc[m][n][j] + bv[n]);
                    }
                }
            }
        }
    }
}

__global__ void k_add(float4* __restrict__ out, const float4* __restrict__ out2, int n4) {
    int i = blockIdx.x * blockDim.x + threadIdx.x;
    const int stride = gridDim.x * blockDim.x;
    #pragma unroll 1
    for (; i < n4; i += stride) {
        float4 a = out[i], c = out2[i];
        a.x += c.x; a.y += c.y; a.z += c.z; a.w += c.w;
        out[i] = a;
    }
}

extern "C" void kernel_launch(void* const* d_in, const int* in_sizes, int n_in,
                              void* d_out, int out_size, void* d_ws, size_t ws_size,
                              hipStream_t stream) {
    const float* x  = (const float*)d_in[0];
    const float* W  = (const float*)d_in[1];
    const float* b  = (const float*)d_in[2];
    const float* Wg = (const float*)d_in[3];
    const float* bg = (const float*)d_in[4];
    float* out = (float*)d_out;
    char* ws = (char*)d_ws;

    int*   counts  = (int*)(ws + CNT_OFF);    // [16]: rank0 experts, rank1 experts
    float* scores2 = (float*)(ws + SC_OFF);
    int*   lists   = (int*)(ws + LIST_OFF);   // [16][NTOK]
    unsigned short* xh = (unsigned short*)(ws + XH_OFF);
    unsigned short* wh = (unsigned short*)(ws + WH_OFF);
    float* out2 = (float*)(ws + O2_OFF);

    int n4w = NEXP * ODIM * DDIM / 4;
    k_cvtw<<<n4w / 256, 256, 0, stream>>>((const float4*)W, (ushort4*)wh, n4w, counts);

    k_gate<<<NTOK / 8, 256, 0, stream>>>(x, Wg, bg, scores2, lists, counts, xh);

    if (ws_size >= WS_NEED) {
        // merged: one dispatch over all 16 lists; rank-0 stores to out,
        // rank-1 stores to out2; then out += out2
        k_gemm<<<1024, 256, 0, stream>>>(xh, wh, counts, lists, scores2, b, out, out2, 0, 16);
        k_add<<<2048, 256, 0, stream>>>((float4*)out, (const float4*)out2, NTOK * ODIM / 4);
    } else {
        // fallback: rank-0 store pass, then rank-1 RMW pass (stream-ordered)
        k_gemm<<<1024, 256, 0, stream>>>(xh, wh, counts, lists, scores2, b, out, nullptr, 0, 8);
        k_gemm<<<1024, 256, 0, stream>>>(xh, wh, counts, lists, scores2, b, out, nullptr, 8, 16);
    }
}